// Round 1
// baseline (1040.554 us; speedup 1.0000x reference)
//
#include <hip/hip_runtime.h>

#define S_LEN  1024
#define D_KK   64
#define N_HEAD 96   // B*H = 8*12

// ---------------- Kernel A: scores + mask + softmax -> attn ----------------
// block = 256 threads (4 waves); each block does 16 q-rows, each wave 4 rows.
// Lane l holds scores for k = l + 64*j, j = 0..15 (full row in 64 VGPRs).
#define TK 256
#define BQ 16

__global__ __launch_bounds__(256, 2) void attn_softmax_kernel(
    const float* __restrict__ Qg, const float* __restrict__ Kg,
    const int* __restrict__ maskg, float* __restrict__ attng)
{
    __shared__ float kt[D_KK][TK + 1]; // transposed K tile [d][k], pad 257 floats
    __shared__ float qs[BQ][68];       // Q tile, padded stride (272 B, 16B aligned)

    const int t    = threadIdx.x;
    const int lane = t & 63;
    const int wave = t >> 6;
    const int head = blockIdx.y;
    const int q0   = blockIdx.x * BQ;
    const int rbase = wave << 2;

    // stage Q tile (16 rows x 64), coalesced float4
    {
        const int r  = t >> 4;
        const int d0 = (t & 15) << 2;
        const float4 qv = *(const float4*)(Qg + ((size_t)head * S_LEN + q0 + r) * D_KK + d0);
        qs[r][d0 + 0] = qv.x; qs[r][d0 + 1] = qv.y;
        qs[r][d0 + 2] = qv.z; qs[r][d0 + 3] = qv.w;
    }

    float s[4][16];

    for (int kt_i = 0; kt_i < S_LEN / TK; ++kt_i) {
        __syncthreads();
        // stage K^T tile: global coalesced float4, LDS write ~conflict-free (pad 257)
        {
            const int d0 = (t & 15) << 2;
            const int kb = t >> 4;
            #pragma unroll
            for (int c = 0; c < TK / 16; ++c) {
                const int kl = c * 16 + kb;
                const float4 kv = *(const float4*)(Kg + ((size_t)head * S_LEN + kt_i * TK + kl) * D_KK + d0);
                kt[d0 + 0][kl] = kv.x;
                kt[d0 + 1][kl] = kv.y;
                kt[d0 + 2][kl] = kv.z;
                kt[d0 + 3][kl] = kv.w;
            }
        }
        __syncthreads();

        float acc[4][4] = {{0.f,0.f,0.f,0.f},{0.f,0.f,0.f,0.f},
                           {0.f,0.f,0.f,0.f},{0.f,0.f,0.f,0.f}};
        for (int d0 = 0; d0 < D_KK; d0 += 4) {
            float4 qv[4];
            #pragma unroll
            for (int r = 0; r < 4; ++r)
                qv[r] = *(const float4*)(&qs[rbase + r][d0]);   // broadcast (free)
            #pragma unroll
            for (int dd = 0; dd < 4; ++dd) {
                float kv[4];
                #pragma unroll
                for (int j = 0; j < 4; ++j)
                    kv[j] = kt[d0 + dd][lane + 64 * j];         // lane-consecutive (free)
                #pragma unroll
                for (int r = 0; r < 4; ++r) {
                    const float qd = (&qv[r].x)[dd];
                    #pragma unroll
                    for (int j = 0; j < 4; ++j)
                        acc[r][j] = fmaf(qd, kv[j], acc[r][j]);
                }
            }
        }
        #pragma unroll
        for (int r = 0; r < 4; ++r)
            #pragma unroll
            for (int j = 0; j < 4; ++j)
                s[r][kt_i * 4 + j] = acc[r][j] * 0.125f;        // *1/sqrt(64)
    }

    // mask + softmax + write attn (coalesced b32: lanes are consecutive k)
    #pragma unroll
    for (int r = 0; r < 4; ++r) {
        const int q = q0 + rbase + r;
        const int*  mrow = maskg + ((size_t)head * S_LEN + q) * S_LEN;
        float*      arow = attng + ((size_t)head * S_LEN + q) * S_LEN;
        float m = -3.0e38f;
        #pragma unroll
        for (int j = 0; j < 16; ++j) {
            if (mrow[lane + 64 * j]) s[r][j] = -1.0e9f;
            m = fmaxf(m, s[r][j]);
        }
        #pragma unroll
        for (int off = 32; off >= 1; off >>= 1)
            m = fmaxf(m, __shfl_xor(m, off, 64));
        float l = 0.0f;
        #pragma unroll
        for (int j = 0; j < 16; ++j) {
            s[r][j] = __expf(s[r][j] - m);
            l += s[r][j];
        }
        #pragma unroll
        for (int off = 32; off >= 1; off >>= 1)
            l += __shfl_xor(l, off, 64);
        const float inv = 1.0f / l;
        #pragma unroll
        for (int j = 0; j < 16; ++j)
            arow[lane + 64 * j] = s[r][j] * inv;
    }
}

// ---------------- Kernel B: context = attn @ V ----------------
// 64(q) x 64(d) output tile per block; thread owns 4x4 in registers.
#define TKB 128

__global__ __launch_bounds__(256, 2) void attn_pv_kernel(
    const float* __restrict__ attng, const float* __restrict__ Vg,
    float* __restrict__ ctxg)
{
    __shared__ float at[64][132];   // attn tile, pad 132 (528 B rows, 16B aligned)
    __shared__ float vt[TKB][68];   // V tile, pad 68 (272 B rows, 16B aligned)

    const int t    = threadIdx.x;
    const int tx   = t & 15;        // d-group
    const int ty   = t >> 4;        // q-group
    const int head = blockIdx.y;
    const int q0   = blockIdx.x * 64;

    float acc[4][4] = {{0.f,0.f,0.f,0.f},{0.f,0.f,0.f,0.f},
                       {0.f,0.f,0.f,0.f},{0.f,0.f,0.f,0.f}};

    for (int k0 = 0; k0 < S_LEN; k0 += TKB) {
        __syncthreads();
        // stage attn tile 64 x 128 (coalesced float4)
        #pragma unroll
        for (int p = 0; p < 8; ++p) {
            const int i  = t + 256 * p;       // float4 units, 0..2047
            const int q  = i >> 5;
            const int kk = (i & 31) << 2;
            const float4 a = *(const float4*)(attng + ((size_t)head * S_LEN + q0 + q) * S_LEN + k0 + kk);
            *(float4*)(&at[q][kk]) = a;
        }
        // stage V tile 128 x 64 (coalesced float4)
        #pragma unroll
        for (int p = 0; p < 8; ++p) {
            const int i  = t + 256 * p;
            const int k  = i >> 4;
            const int d0 = (i & 15) << 2;
            const float4 v = *(const float4*)(Vg + ((size_t)head * S_LEN + k0 + k) * D_KK + d0);
            *(float4*)(&vt[k][d0]) = v;
        }
        __syncthreads();

        for (int k = 0; k < TKB; ++k) {
            const float4 v = *(const float4*)(&vt[k][tx << 2]);  // 2-way (free)
            #pragma unroll
            for (int qq = 0; qq < 4; ++qq) {
                const float a = at[(ty << 2) + qq][k];           // broadcast across tx
                acc[qq][0] = fmaf(a, v.x, acc[qq][0]);
                acc[qq][1] = fmaf(a, v.y, acc[qq][1]);
                acc[qq][2] = fmaf(a, v.z, acc[qq][2]);
                acc[qq][3] = fmaf(a, v.w, acc[qq][3]);
            }
        }
    }

    #pragma unroll
    for (int qq = 0; qq < 4; ++qq) {
        float4 o;
        o.x = acc[qq][0]; o.y = acc[qq][1]; o.z = acc[qq][2]; o.w = acc[qq][3];
        *(float4*)(ctxg + ((size_t)head * S_LEN + q0 + (ty << 2) + qq) * D_KK + (tx << 2)) = o;
    }
}

extern "C" void kernel_launch(void* const* d_in, const int* in_sizes, int n_in,
                              void* d_out, int out_size, void* d_ws, size_t ws_size,
                              hipStream_t stream) {
    const float* Q    = (const float*)d_in[0];
    const float* K    = (const float*)d_in[1];
    const float* V    = (const float*)d_in[2];
    const int*   mask = (const int*)d_in[3];

    float* ctx  = (float*)d_out;                                // [B,H,S,D] first
    float* attn = ctx + (size_t)N_HEAD * S_LEN * D_KK;          // then [B,H,S,S]

    dim3 gridA(S_LEN / BQ, N_HEAD);
    attn_softmax_kernel<<<gridA, 256, 0, stream>>>(Q, K, mask, attn);

    dim3 gridB(S_LEN / 64, N_HEAD);
    attn_pv_kernel<<<gridB, 256, 0, stream>>>(attn, V, ctx);
}